// Round 1
// baseline (669.133 us; speedup 1.0000x reference)
//
#include <hip/hip_runtime.h>
#include <hip/hip_fp16.h>

#define G_ 512
#define B_ 64
#define I_ 32
#define H_ 64
#define NGATE 256  // 4*H

typedef _Float16 half8 __attribute__((ext_vector_type(8)));
typedef float f32x4 __attribute__((ext_vector_type(4)));

__device__ __forceinline__ float sigf(float x) {
  return 1.0f / (1.0f + __expf(-x));
}
__device__ __forceinline__ float tanh_fast(float x) {
  x = fminf(fmaxf(x, -15.0f), 15.0f);
  float e = __expf(2.0f * x);
  return (e - 1.0f) / (e + 1.0f);
}

// ---------------- K1: xproj[g][b][j] = input[g,b,:] . W_ih[j,:] + b_ih[j] + b_hh[j]
__global__ __launch_bounds__(256) void k_xproj(
    const float* __restrict__ input, const float* __restrict__ W_ih,
    const float* __restrict__ b_ih, const float* __restrict__ b_hh,
    _Float16* __restrict__ xproj) {
  const int g = blockIdx.x;
  const int j = threadIdx.x;
  __shared__ alignas(16) float inp[B_ * I_];
  const float* ing = input + (size_t)g * (B_ * I_);
#pragma unroll
  for (int t = 0; t < (B_ * I_) / 256; ++t) inp[t * 256 + j] = ing[t * 256 + j];
  float w[I_];
#pragma unroll
  for (int k = 0; k < I_; k += 4) {
    f32x4 v = *(const f32x4*)(W_ih + j * I_ + k);
    w[k] = v[0]; w[k + 1] = v[1]; w[k + 2] = v[2]; w[k + 3] = v[3];
  }
  const float bias = b_ih[j] + b_hh[j];
  __syncthreads();
  for (int b = 0; b < B_; ++b) {
    float a0 = bias, a1 = 0.f, a2 = 0.f, a3 = 0.f;
#pragma unroll
    for (int k = 0; k < I_; k += 4) {
      f32x4 iv = *(const f32x4*)&inp[b * I_ + k];
      a0 += iv[0] * w[k]; a1 += iv[1] * w[k + 1];
      a2 += iv[2] * w[k + 2]; a3 += iv[3] * w[k + 3];
    }
    xproj[((size_t)g * B_ + b) * NGATE + j] = (_Float16)((a0 + a1) + (a2 + a3));
  }
}

// ---------------- K2: per-batch-row LSTM scan. 64 blocks x 256 threads.
// Thread j owns gate row j (W_hh row in regs); h lives in LDS (broadcast reads).
__global__ __launch_bounds__(256) void k_scan(
    const _Float16* __restrict__ xproj, const float* __restrict__ h0,
    const float* __restrict__ c0, const float* __restrict__ W_hh,
    _Float16* __restrict__ hs) {
  const int b = blockIdx.x;
  const int j = threadIdx.x;
  __shared__ alignas(16) float hsh[H_];
  __shared__ float gates[NGATE];
  float w[H_];
#pragma unroll
  for (int k = 0; k < H_; k += 4) {
    f32x4 v = *(const f32x4*)(W_hh + j * H_ + k);
    w[k] = v[0]; w[k + 1] = v[1]; w[k + 2] = v[2]; w[k + 3] = v[3];
  }
  float c = 0.0f;
  if (j < H_) {
    hsh[j] = h0[b * H_ + j];
    c = c0[b * H_ + j];
  }
  __syncthreads();
  float xg = (float)xproj[((size_t)0 * B_ + b) * NGATE + j];
  for (int g = 0; g < G_; ++g) {
    _Float16 xn = (_Float16)0.0f;
    if (g + 1 < G_) xn = xproj[((size_t)(g + 1) * B_ + b) * NGATE + j];
    float a0 = xg, a1 = 0.f, a2 = 0.f, a3 = 0.f;
#pragma unroll
    for (int k = 0; k < H_; k += 4) {
      f32x4 hv = *(const f32x4*)&hsh[k];
      a0 += hv[0] * w[k]; a1 += hv[1] * w[k + 1];
      a2 += hv[2] * w[k + 2]; a3 += hv[3] * w[k + 3];
    }
    gates[j] = (a0 + a1) + (a2 + a3);
    __syncthreads();
    if (j < H_) {
      float ig = sigf(gates[j]);
      float fg = sigf(gates[H_ + j]);
      float gg = tanh_fast(gates[2 * H_ + j]);
      float og = sigf(gates[3 * H_ + j]);
      c = fg * c + ig * gg;
      float hh = og * tanh_fast(c);
      hsh[j] = hh;
      hs[(size_t)b * (G_ * H_) + (size_t)g * H_ + j] = (_Float16)hh;
    }
    __syncthreads();
    xg = (float)xn;
  }
}

// ---------------- K3/K5/K7: skinny GEMM part[ks][m][n] = X[m,kchunk] . W[n,kchunk]
// X: [64][K] f16, W: [N][K] fp32 (converted to f16 in-flight), MFMA 16x16x32 f16.
__global__ __launch_bounds__(256) void k_gemm(
    const _Float16* __restrict__ X, const float* __restrict__ W,
    float* __restrict__ part, int N, int K, int KC, int ntiles) {
  const int bid = blockIdx.x;
  const int n0 = (bid % ntiles) * 64;
  const int ks = bid / ntiles;
  const int kbeg = ks * KC;
  const int lane = threadIdx.x & 63;
  const int wave = threadIdx.x >> 6;
  const int r = lane & 15;
  const int gq = lane >> 4;
  const int ncol = n0 + wave * 16 + r;
  const float* wrow = W + (size_t)ncol * K + 8 * gq;
  const _Float16* xrow = X + (size_t)r * K + 8 * gq;
  f32x4 acc[4] = {};
#pragma unroll 2
  for (int k = kbeg; k < kbeg + KC; k += 32) {
    f32x4 blo = *(const f32x4*)(wrow + k);
    f32x4 bhi = *(const f32x4*)(wrow + k + 4);
    half8 bf;
    bf[0] = (_Float16)blo[0]; bf[1] = (_Float16)blo[1];
    bf[2] = (_Float16)blo[2]; bf[3] = (_Float16)blo[3];
    bf[4] = (_Float16)bhi[0]; bf[5] = (_Float16)bhi[1];
    bf[6] = (_Float16)bhi[2]; bf[7] = (_Float16)bhi[3];
#pragma unroll
    for (int mi = 0; mi < 4; ++mi) {
      half8 af = *(const half8*)(xrow + (size_t)(mi * 16) * K + k);
      acc[mi] = __builtin_amdgcn_mfma_f32_16x16x32_f16(af, bf, acc[mi], 0, 0, 0);
    }
  }
#pragma unroll
  for (int mi = 0; mi < 4; ++mi) {
#pragma unroll
    for (int q = 0; q < 4; ++q) {
      int row = mi * 16 + gq * 4 + q;
      part[((size_t)ks * 64 + row) * N + n0 + wave * 16 + r] = acc[mi][q];
    }
  }
}

// ---------------- K4/K6: sum k-split partials + bias -> f16 activations
__global__ __launch_bounds__(256) void k_reduce(
    const float* __restrict__ part, const float* __restrict__ bias,
    _Float16* __restrict__ out, int N, int ksplit) {
  const int idx = blockIdx.x * 256 + threadIdx.x;
  const int n = idx % N;
  float s = bias[n];
  for (int ks = 0; ks < ksplit; ++ks) s += part[(size_t)ks * 64 * N + idx];
  out[idx] = (_Float16)s;
}

// ---------------- K8: final reduce + bias + sigmoid -> fp32 output
__global__ __launch_bounds__(256) void k_reduce_sig(
    const float* __restrict__ part, const float* __restrict__ bias,
    float* __restrict__ out, int N, int ksplit) {
  const int idx = blockIdx.x * 256 + threadIdx.x;
  const int n = idx % N;
  float s = bias[n];
  for (int ks = 0; ks < ksplit; ++ks) s += part[(size_t)ks * 64 * N + idx];
  out[idx] = sigf(s);
}

extern "C" void kernel_launch(void* const* d_in, const int* in_sizes, int n_in,
                              void* d_out, int out_size, void* d_ws, size_t ws_size,
                              hipStream_t stream) {
  const float* input = (const float*)d_in[0];
  const float* h0    = (const float*)d_in[1];
  const float* c0    = (const float*)d_in[2];
  const float* W_ih  = (const float*)d_in[3];
  const float* W_hh  = (const float*)d_in[4];
  const float* b_ih  = (const float*)d_in[5];
  const float* b_hh  = (const float*)d_in[6];
  const float* W1    = (const float*)d_in[7];
  const float* b1    = (const float*)d_in[8];
  const float* W2    = (const float*)d_in[9];
  const float* b2    = (const float*)d_in[10];
  const float* W3    = (const float*)d_in[11];
  const float* b3    = (const float*)d_in[12];
  float* out = (float*)d_out;

  // Workspace layout (26,148,864 B total):
  //   [0, 20971520)        part union (GEMM partials; also xproj overlay, 16.7 MB, dead after scan)
  //   [20971520, 25165824) hs_f16  [64][32768]
  //   [25165824, 25821184) x2_f16  [64][5120]
  //   [25821184, 26148864) x3_f16  [64][2560]
  uint8_t* ws = (uint8_t*)d_ws;
  float*    part  = (float*)ws;
  _Float16* xproj = (_Float16*)ws;
  _Float16* hs    = (_Float16*)(ws + 20971520);
  _Float16* x2    = (_Float16*)(ws + 25165824);
  _Float16* x3    = (_Float16*)(ws + 25821184);

  k_xproj<<<G_, 256, 0, stream>>>(input, W_ih, b_ih, b_hh, xproj);
  k_scan<<<B_, 256, 0, stream>>>(xproj, h0, c0, W_hh, hs);
  // GEMM1: [64,32768] x W1[5120,32768]^T, ksplit=16 (KC=2048), 80 n-tiles -> 1280 blocks
  k_gemm<<<80 * 16, 256, 0, stream>>>(hs, W1, part, 5120, 32768, 2048, 80);
  k_reduce<<<(64 * 5120) / 256, 256, 0, stream>>>(part, b1, x2, 5120, 16);
  // GEMM2: [64,5120] x W2[2560,5120]^T, ksplit=8 (KC=640), 40 n-tiles -> 320 blocks
  k_gemm<<<40 * 8, 256, 0, stream>>>(x2, W2, part, 2560, 5120, 640, 40);
  k_reduce<<<(64 * 2560) / 256, 256, 0, stream>>>(part, b2, x3, 2560, 8);
  // GEMM3: [64,2560] x W3[512,2560]^T, ksplit=8 (KC=320), 8 n-tiles -> 64 blocks
  k_gemm<<<8 * 8, 256, 0, stream>>>(x3, W3, part, 512, 2560, 320, 8);
  k_reduce_sig<<<(64 * 512) / 256, 256, 0, stream>>>(part, b3, out, 512, 8);
}

// Round 2
// 587.430 us; speedup vs baseline: 1.1391x; 1.1391x over previous
//
#include <hip/hip_runtime.h>
#include <hip/hip_fp16.h>

#define G_ 512
#define B_ 64
#define I_ 32
#define H_ 64
#define NGATE 256  // 4*H

typedef _Float16 half8 __attribute__((ext_vector_type(8)));
typedef _Float16 h2 __attribute__((ext_vector_type(2)));
typedef float f32x4 __attribute__((ext_vector_type(4)));

#if __has_builtin(__builtin_amdgcn_fdot2)
#define FDOT2(a, b, c) __builtin_amdgcn_fdot2((a), (b), (c), false)
#else
#define FDOT2(a, b, c) ((c) + (float)(a)[0] * (float)(b)[0] + (float)(a)[1] * (float)(b)[1])
#endif

__device__ __forceinline__ float sigf(float x) {
  return 1.0f / (1.0f + __expf(-x));
}
__device__ __forceinline__ float tanh_fast(float x) {
  x = fminf(fmaxf(x, -15.0f), 15.0f);
  float e = __expf(2.0f * x);
  return (e - 1.0f) / (e + 1.0f);
}

// ---------------- K1: xproj[g][b][j] = input[g,b,:] . W_ih[j,:] + b_ih[j] + b_hh[j]
__global__ __launch_bounds__(256) void k_xproj(
    const float* __restrict__ input, const float* __restrict__ W_ih,
    const float* __restrict__ b_ih, const float* __restrict__ b_hh,
    _Float16* __restrict__ xproj) {
  const int g = blockIdx.x;
  const int j = threadIdx.x;
  __shared__ alignas(16) float inp[B_ * I_];
  const float* ing = input + (size_t)g * (B_ * I_);
#pragma unroll
  for (int t = 0; t < (B_ * I_) / 256; ++t) inp[t * 256 + j] = ing[t * 256 + j];
  float w[I_];
#pragma unroll
  for (int k = 0; k < I_; k += 4) {
    f32x4 v = *(const f32x4*)(W_ih + j * I_ + k);
    w[k] = v[0]; w[k + 1] = v[1]; w[k + 2] = v[2]; w[k + 3] = v[3];
  }
  const float bias = b_ih[j] + b_hh[j];
  __syncthreads();
  for (int b = 0; b < B_; ++b) {
    float a0 = bias, a1 = 0.f, a2 = 0.f, a3 = 0.f;
#pragma unroll
    for (int k = 0; k < I_; k += 4) {
      f32x4 iv = *(const f32x4*)&inp[b * I_ + k];
      a0 += iv[0] * w[k]; a1 += iv[1] * w[k + 1];
      a2 += iv[2] * w[k + 2]; a3 += iv[3] * w[k + 3];
    }
    xproj[((size_t)g * B_ + b) * NGATE + j] = (_Float16)((a0 + a1) + (a2 + a3));
  }
}

// ---------------- K2: LSTM scan, one wave per batch row, barrier-free.
// Lane j owns hidden column j: gate rows j, 64+j, 128+j, 192+j of W_hh as
// packed f16 in VGPRs (128 regs); h broadcast via 128 B of LDS; dot via
// v_dot2_f32_f16 (f16 products, fp32 accumulate).
__global__ __launch_bounds__(64) void k_scan(
    const _Float16* __restrict__ xproj, const float* __restrict__ h0,
    const float* __restrict__ c0, const float* __restrict__ W_hh,
    _Float16* __restrict__ hs) {
  const int b = blockIdx.x;
  const int j = threadIdx.x;  // 0..63
  __shared__ alignas(16) _Float16 hsh[H_];

  h2 w[4][32];
#pragma unroll
  for (int q = 0; q < 4; ++q) {
    const float* wr = W_hh + (size_t)(q * H_ + j) * H_;
#pragma unroll
    for (int k = 0; k < 32; ++k) {
      h2 t;
      t[0] = (_Float16)wr[2 * k];
      t[1] = (_Float16)wr[2 * k + 1];
      w[q][k] = t;
    }
  }
  float c = c0[b * H_ + j];
  hsh[j] = (_Float16)h0[b * H_ + j];

  const _Float16* xp = xproj + (size_t)b * NGATE;
  float xg[4], xn[4];
#pragma unroll
  for (int q = 0; q < 4; ++q) xg[q] = (float)xp[q * H_ + j];

  for (int g = 0; g < G_; ++g) {
    // prefetch next step's x-projection (hides global latency under the dots)
    if (g + 1 < G_) {
      const _Float16* xq = xp + (size_t)(g + 1) * (B_ * NGATE);
#pragma unroll
      for (int q = 0; q < 4; ++q) xn[q] = (float)xq[q * H_ + j];
    }
    __syncthreads();  // 1-wave block: compiles to cheap waitcnt+barrier; orders hsh
    const h2* hp = (const h2*)hsh;
    float a[4], a2[4];
#pragma unroll
    for (int q = 0; q < 4; ++q) { a[q] = xg[q]; a2[q] = 0.0f; }
#pragma unroll
    for (int k = 0; k < 16; ++k) {
      h2 hv = hp[k];
#pragma unroll
      for (int q = 0; q < 4; ++q) a[q] = FDOT2(hv, w[q][k], a[q]);
    }
#pragma unroll
    for (int k = 16; k < 32; ++k) {
      h2 hv = hp[k];
#pragma unroll
      for (int q = 0; q < 4; ++q) a2[q] = FDOT2(hv, w[q][k], a2[q]);
    }
#pragma unroll
    for (int q = 0; q < 4; ++q) a[q] += a2[q];

    float ig = sigf(a[0]);
    float fg = sigf(a[1]);
    float gg = tanh_fast(a[2]);
    float og = sigf(a[3]);
    c = fg * c + ig * gg;
    float hh = og * tanh_fast(c);
    _Float16 hf = (_Float16)hh;
    __syncthreads();  // all lanes done reading hsh before overwrite
    hsh[j] = hf;
    hs[(size_t)b * (G_ * H_) + (size_t)g * H_ + j] = hf;
#pragma unroll
    for (int q = 0; q < 4; ++q) xg[q] = xn[q];
  }
}

// ---------------- GEMM: part[ks][m][n] = X[m, kchunk] . W[n, kchunk]
// X: [64][K] f16; W: [N][K] fp32 converted to f16 in-flight; MFMA 16x16x32 f16.
template <int N, int K, int KC, int NTILES>
__global__ __launch_bounds__(256) void k_gemm(
    const _Float16* __restrict__ X, const float* __restrict__ W,
    float* __restrict__ part) {
  const int bid = blockIdx.x;
  const int n0 = (bid % NTILES) * 64;
  const int ks = bid / NTILES;
  const int lane = threadIdx.x & 63;
  const int wave = threadIdx.x >> 6;
  const int r = lane & 15;
  const int gq = lane >> 4;
  const int ncol = n0 + wave * 16 + r;
  const float* wrow = W + (size_t)ncol * K + 8 * gq + (size_t)ks * KC;
  const _Float16* xrow = X + (size_t)r * K + 8 * gq + (size_t)ks * KC;
  f32x4 acc[4] = {};
#pragma unroll 4
  for (int k = 0; k < KC; k += 32) {
    f32x4 blo = *(const f32x4*)(wrow + k);
    f32x4 bhi = *(const f32x4*)(wrow + k + 4);
    half8 bf;
    bf[0] = (_Float16)blo[0]; bf[1] = (_Float16)blo[1];
    bf[2] = (_Float16)blo[2]; bf[3] = (_Float16)blo[3];
    bf[4] = (_Float16)bhi[0]; bf[5] = (_Float16)bhi[1];
    bf[6] = (_Float16)bhi[2]; bf[7] = (_Float16)bhi[3];
#pragma unroll
    for (int mi = 0; mi < 4; ++mi) {
      half8 af = *(const half8*)(xrow + (size_t)(mi * 16) * K + k);
      acc[mi] = __builtin_amdgcn_mfma_f32_16x16x32_f16(af, bf, acc[mi], 0, 0, 0);
    }
  }
#pragma unroll
  for (int mi = 0; mi < 4; ++mi) {
#pragma unroll
    for (int q = 0; q < 4; ++q) {
      int row = mi * 16 + gq * 4 + q;
      part[((size_t)ks * 64 + row) * N + n0 + wave * 16 + r] = acc[mi][q];
    }
  }
}

// ---------------- reduce k-split partials + bias -> f16 activations (x4 vectorized)
template <int N, int KS>
__global__ __launch_bounds__(256) void k_reduce(
    const float* __restrict__ part, const float* __restrict__ bias,
    _Float16* __restrict__ out) {
  const int idx4 = (blockIdx.x * 256 + threadIdx.x) * 4;
  const int n = idx4 % N;
  f32x4 s = *(const f32x4*)(bias + n);
#pragma unroll
  for (int ks = 0; ks < KS; ++ks) s += *(const f32x4*)(part + (size_t)ks * 64 * N + idx4);
#pragma unroll
  for (int t = 0; t < 4; ++t) out[idx4 + t] = (_Float16)s[t];
}

// ---------------- final reduce + bias + sigmoid -> fp32 output
template <int N, int KS>
__global__ __launch_bounds__(256) void k_reduce_sig(
    const float* __restrict__ part, const float* __restrict__ bias,
    float* __restrict__ out) {
  const int idx4 = (blockIdx.x * 256 + threadIdx.x) * 4;
  const int n = idx4 % N;
  f32x4 s = *(const f32x4*)(bias + n);
#pragma unroll
  for (int ks = 0; ks < KS; ++ks) s += *(const f32x4*)(part + (size_t)ks * 64 * N + idx4);
#pragma unroll
  for (int t = 0; t < 4; ++t) out[idx4 + t] = sigf(s[t]);
}

extern "C" void kernel_launch(void* const* d_in, const int* in_sizes, int n_in,
                              void* d_out, int out_size, void* d_ws, size_t ws_size,
                              hipStream_t stream) {
  const float* input = (const float*)d_in[0];
  const float* h0    = (const float*)d_in[1];
  const float* c0    = (const float*)d_in[2];
  const float* W_ih  = (const float*)d_in[3];
  const float* W_hh  = (const float*)d_in[4];
  const float* b_ih  = (const float*)d_in[5];
  const float* b_hh  = (const float*)d_in[6];
  const float* W1    = (const float*)d_in[7];
  const float* b1    = (const float*)d_in[8];
  const float* W2    = (const float*)d_in[9];
  const float* b2    = (const float*)d_in[10];
  const float* W3    = (const float*)d_in[11];
  const float* b3    = (const float*)d_in[12];
  float* out = (float*)d_out;

  // Workspace layout (~47.1 MB of the ~2.6 GB ws):
  //   [0, 41943040)            part (GEMM partials, max ks=32 x 64 x 5120 fp32);
  //                            also xproj overlay (16.8 MB, dead before GEMM1)
  //   [41943040, 46137344)     hs_f16 [64][32768]
  //   [46137344, 46792704)     x2_f16 [64][5120]
  //   [46792704, 47120384)     x3_f16 [64][2560]
  uint8_t* ws = (uint8_t*)d_ws;
  float*    part  = (float*)ws;
  _Float16* xproj = (_Float16*)ws;
  _Float16* hs    = (_Float16*)(ws + 41943040);
  _Float16* x2    = (_Float16*)(ws + 46137344);
  _Float16* x3    = (_Float16*)(ws + 46792704);

  k_xproj<<<G_, 256, 0, stream>>>(input, W_ih, b_ih, b_hh, xproj);
  k_scan<<<B_, 64, 0, stream>>>(xproj, h0, c0, W_hh, hs);
  // GEMM1: [64,32768] x W1[5120,32768]^T, ksplit=32 (KC=1024), 80 n-tiles -> 2560 blocks
  k_gemm<5120, 32768, 1024, 80><<<80 * 32, 256, 0, stream>>>(hs, W1, part);
  k_reduce<5120, 32><<<(64 * 5120) / 4 / 256, 256, 0, stream>>>(part, b1, x2);
  // GEMM2: [64,5120] x W2[2560,5120]^T, ksplit=8 (KC=640), 40 n-tiles -> 320 blocks
  k_gemm<2560, 5120, 640, 40><<<40 * 8, 256, 0, stream>>>(x2, W2, part);
  k_reduce<2560, 8><<<(64 * 2560) / 4 / 256, 256, 0, stream>>>(part, b2, x3);
  // GEMM3: [64,2560] x W3[512,2560]^T, ksplit=8 (KC=320), 8 n-tiles -> 64 blocks
  k_gemm<512, 2560, 320, 8><<<8 * 8, 256, 0, stream>>>(x3, W3, part);
  k_reduce_sig<512, 8><<<(64 * 512) / 4 / 256, 256, 0, stream>>>(part, b3, out);
}